// Round 4
// baseline (467.850 us; speedup 1.0000x reference)
//
#include <hip/hip_runtime.h>
#include <math.h>

#define DD 256
#define MM 2048
#define NN 512

typedef float f32x4 __attribute__((ext_vector_type(4)));

__device__ inline f32x4 ld_nt(const f32x4* p) { return __builtin_nontemporal_load(p); }

// blocks 0..255:   W1[d][j]  = (1/16) * sum_a wq[a][d]*wk[a][j]   (qt = q_vec @ W1)
// blocks 256..511: W2T[d][j] = sum_e wo[j][e]*wv[e][d]            (out = c @ W2T)
__global__ void prep_weights(const float* __restrict__ wq, const float* __restrict__ wk,
                             const float* __restrict__ wv, const float* __restrict__ wo,
                             float* __restrict__ W1, float* __restrict__ W2T) {
    __shared__ float sA[DD];
    const int j = threadIdx.x;
    const int b = blockIdx.x;
    if (b < DD) {
        const int d = b;
        sA[j] = wq[j * DD + d];
        __syncthreads();
        float acc = 0.f;
        for (int a = 0; a < DD; ++a) acc = fmaf(sA[a], wk[a * DD + j], acc);
        W1[d * DD + j] = acc * 0.0625f;
    } else {
        const int d = b - DD;
        sA[j] = wv[j * DD + d];
        __syncthreads();
        float acc = 0.f;
        for (int e = 0; e < DD; ++e) acc = fmaf(wo[j * DD + e], sA[e], acc);
        W2T[d * DD + j] = acc;
    }
}

// One block per 2 m-rows (grid 1024 = 4 blocks/CU, single occupancy round).
// kv for rows (m0, m0+1) is one contiguous 64-tile stream per wave.
// Depth-2 register pipeline; tiles 0,1 issued BEFORE the qt-prologue so HBM
// stays busy while the block does its L2-latency-bound W1 loads.
__global__ __launch_bounds__(256, 4)
void attn_fused(const float* __restrict__ q_vec, const float* __restrict__ kv,
                const float* __restrict__ W1, const float* __restrict__ W2T,
                float* __restrict__ out, float* __restrict__ attn_out) {
    __shared__ float s_pe[NN];
    __shared__ float s_lw[4];
    __shared__ float s_wc[4][DD];
    __shared__ float s_qa[DD], s_qb[DD];     // q rows; reused as normalized c rows
    __shared__ float s_qt0[DD], s_qt1[DD];

    const int m0   = blockIdx.x * 2;
    const int tid  = threadIdx.x;
    const int wave = tid >> 6;
    const int lane = tid & 63;
    const int grp  = lane >> 4;
    const int l16  = lane & 15;
    const int nbase = wave * 4 + grp;

    const f32x4* kvb = (const f32x4*)(kv + (size_t)m0 * NN * DD);
    const int lofs   = nbase * 64 + l16;   // lane's f4-offset within a 16-row tile
    const int STRIDE = 16 * 64;            // 16 rows, f4 units
    const int NT     = 2 * NN / 16;        // 64 tiles across both rows

    // ---- early prefetch: tiles 0 and 1 (keeps HBM busy through prologue) ----
    f32x4 A0, A1, A2, A3, P0, P1, P2, P3;
    {
        const f32x4* p = kvb + lofs;
        A0 = ld_nt(p); A1 = ld_nt(p + 16); A2 = ld_nt(p + 32); A3 = ld_nt(p + 48);
        const f32x4* q = kvb + STRIDE + lofs;
        P0 = ld_nt(q); P1 = ld_nt(q + 16); P2 = ld_nt(q + 32); P3 = ld_nt(q + 48);
    }

    // ---- prologue: qt rows for m0 and m0+1 (one W1 traversal) ----
    s_qa[tid] = q_vec[(size_t)m0 * DD + tid];
    s_qb[tid] = q_vec[(size_t)m0 * DD + DD + tid];
    __syncthreads();
    {
        float t0 = 0.f, t1 = 0.f;
#pragma unroll 8
        for (int d = 0; d < DD; ++d) {
            const float w = W1[d * DD + tid];
            t0 = fmaf(s_qa[d], w, t0);
            t1 = fmaf(s_qb[d], w, t1);
        }
        s_qt0[tid] = t0;
        s_qt1[tid] = t1;
    }
    __syncthreads();

    for (int r = 0; r < 2; ++r) {
        const f32x4* qt4 = (const f32x4*)(r == 0 ? s_qt0 : s_qt1);
        const f32x4 qv0 = qt4[l16];
        const f32x4 qv1 = qt4[l16 + 16];
        const f32x4 qv2 = qt4[l16 + 32];
        const f32x4 qv3 = qt4[l16 + 48];

        f32x4 c0 = (f32x4)0.f, c1 = (f32x4)0.f, c2 = (f32x4)0.f, c3 = (f32x4)0.f;
        float lw = 0.f;

        for (int it = 0; it < NN / 16; ++it) {
            const int g = r * (NN / 16) + it;
            f32x4 N0, N1, N2, N3;
            const bool pf = (g + 2 < NT);
            if (pf) {
                const f32x4* np = kvb + (size_t)(g + 2) * STRIDE + lofs;
                N0 = ld_nt(np); N1 = ld_nt(np + 16); N2 = ld_nt(np + 32); N3 = ld_nt(np + 48);
            }

            f32x4 t = A0 * qv0 + A1 * qv1 + A2 * qv2 + A3 * qv3;
            float pd = (t[0] + t[1]) + (t[2] + t[3]);
            pd += __shfl_xor(pd, 1);
            pd += __shfl_xor(pd, 2);
            pd += __shfl_xor(pd, 4);
            pd += __shfl_xor(pd, 8);

            const float pe = __expf(pd);
            if (l16 == 0) s_pe[it * 16 + nbase] = pe;
            lw += pe;

            c0 += pe * A0; c1 += pe * A1; c2 += pe * A2; c3 += pe * A3;

            A0 = P0; A1 = P1; A2 = P2; A3 = P3;
            if (pf) { P0 = N0; P1 = N1; P2 = N2; P3 = N3; }
        }

        // cross-group reduce within the wave (lanes ^16, ^32)
#pragma unroll
        for (int i = 0; i < 4; ++i) {
            c0[i] += __shfl_xor(c0[i], 16); c1[i] += __shfl_xor(c1[i], 16);
            c2[i] += __shfl_xor(c2[i], 16); c3[i] += __shfl_xor(c3[i], 16);
            c0[i] += __shfl_xor(c0[i], 32); c1[i] += __shfl_xor(c1[i], 32);
            c2[i] += __shfl_xor(c2[i], 32); c3[i] += __shfl_xor(c3[i], 32);
        }
        lw += __shfl_xor(lw, 16);
        lw += __shfl_xor(lw, 32);

        {
            f32x4* wc4 = (f32x4*)(&s_wc[wave][0]);
            const f32x4 cg = (grp == 0) ? c0 : (grp == 1) ? c1 : (grp == 2) ? c2 : c3;
            wc4[grp * 16 + l16] = cg;
            if (lane == 0) s_lw[wave] = lw;
        }
        __syncthreads();

        const float L = (s_lw[0] + s_lw[1]) + (s_lw[2] + s_lw[3]);
        const float invL = 1.f / L;
        const float cd = ((s_wc[0][tid] + s_wc[1][tid]) + (s_wc[2][tid] + s_wc[3][tid])) * invL;

        if (r == 0) s_qa[tid] = cd; else s_qb[tid] = cd;
        attn_out[(size_t)(m0 + r) * NN + tid]       = s_pe[tid] * invL;
        attn_out[(size_t)(m0 + r) * NN + tid + 256] = s_pe[tid + 256] * invL;
        __syncthreads();   // s_pe / s_wc reused next r-iteration
    }

    // ---- epilogue: out rows for m0 and m0+1 (one W2T traversal) ----
    {
        float o0 = 0.f, o1 = 0.f;
#pragma unroll 8
        for (int d = 0; d < DD; ++d) {
            const float w = W2T[d * DD + tid];
            o0 = fmaf(s_qa[d], w, o0);
            o1 = fmaf(s_qb[d], w, o1);
        }
        out[(size_t)m0 * DD + tid]      = o0;
        out[(size_t)m0 * DD + DD + tid] = o1;
    }
}

extern "C" void kernel_launch(void* const* d_in, const int* in_sizes, int n_in,
                              void* d_out, int out_size, void* d_ws, size_t ws_size,
                              hipStream_t stream) {
    const float* q_vec = (const float*)d_in[0];
    const float* kv    = (const float*)d_in[1];
    const float* wq    = (const float*)d_in[2];
    const float* wk    = (const float*)d_in[3];
    const float* wv    = (const float*)d_in[4];
    const float* wo    = (const float*)d_in[5];

    float* out  = (float*)d_out;                     // [M, D]
    float* attn = (float*)d_out + (size_t)MM * DD;   // [M, N]

    float* W1  = (float*)d_ws;                       // [D, D] (1/16 folded)
    float* W2T = W1 + DD * DD;                       // [D, D] = (wo@wv).T

    prep_weights<<<2 * DD, DD, 0, stream>>>(wq, wk, wv, wo, W1, W2T);
    attn_fused<<<MM / 2, DD, 0, stream>>>(q_vec, kv, W1, W2T, out, attn);
}

// Round 5
// 229.047 us; speedup vs baseline: 2.0426x; 2.0426x over previous
//
#include <hip/hip_runtime.h>
#include <math.h>

#define DD 256
#define MM 2048
#define NN 512

typedef float f32x4 __attribute__((ext_vector_type(4)));

__device__ inline f32x4 ld_nt(const f32x4* p) { return __builtin_nontemporal_load(p); }

// blocks 0..255:   W1[d][j]  = (1/16) * sum_a wq[a][d]*wk[a][j]   (qt = q_vec @ W1)
// blocks 256..511: W2T[d][j] = sum_e wo[j][e]*wv[e][d]            (out = c @ W2T)
__global__ void prep_weights(const float* __restrict__ wq, const float* __restrict__ wk,
                             const float* __restrict__ wv, const float* __restrict__ wo,
                             float* __restrict__ W1, float* __restrict__ W2T) {
    __shared__ float sA[DD];
    const int j = threadIdx.x;
    const int b = blockIdx.x;
    if (b < DD) {
        const int d = b;
        sA[j] = wq[j * DD + d];
        __syncthreads();
        float acc = 0.f;
        for (int a = 0; a < DD; ++a) acc = fmaf(sA[a], wk[a * DD + j], acc);
        W1[d * DD + j] = acc * 0.0625f;
    } else {
        const int d = b - DD;
        sA[j] = wv[j * DD + d];
        __syncthreads();
        float acc = 0.f;
        for (int e = 0; e < DD; ++e) acc = fmaf(wo[j * DD + e], sA[e], acc);
        W2T[d * DD + j] = acc;
    }
}

// Y[m][j] = sum_d X[m][d] * W[d*DD + j]; ROWS rows per block, 256 threads.
template <int ROWS>
__global__ void rowgemm(const float* __restrict__ X, const float* __restrict__ W,
                        float* __restrict__ Y) {
    __shared__ float sX[ROWS][DD];
    const int j = threadIdx.x;
    const int m0 = blockIdx.x * ROWS;
    for (int r = 0; r < ROWS; ++r) sX[r][j] = X[(size_t)(m0 + r) * DD + j];
    __syncthreads();
    float acc[ROWS];
#pragma unroll
    for (int r = 0; r < ROWS; ++r) acc[r] = 0.f;
    for (int d = 0; d < DD; ++d) {
        const float w = W[d * DD + j];
#pragma unroll
        for (int r = 0; r < ROWS; ++r) acc[r] = fmaf(sX[r][d], w, acc[r]);
    }
    for (int r = 0; r < ROWS; ++r) Y[(size_t)(m0 + r) * DD + j] = acc[r];
}

// One block per m; 4 waves; 16 lanes per n-row (4 rows/wave/iter).
// EXACT inner-loop/register structure of the 208.8us kernel (A + b depth-1
// prefetch, nt loads). Changes: qt precomputed (single coalesced row load,
// issued AFTER tile-0 prefetch), epilogue removed (writes normalized c to ws).
__global__ __launch_bounds__(256, 4)
void attn_stream(const float* __restrict__ kv, const float* __restrict__ qt,
                 float* __restrict__ c_out, float* __restrict__ attn_out) {
    __shared__ float s_pe[NN];
    __shared__ float s_lw[4];
    __shared__ float s_wc[4][DD];
    __shared__ float s_qt[DD];

    const int m    = blockIdx.x;
    const int tid  = threadIdx.x;
    const int wave = tid >> 6;
    const int lane = tid & 63;
    const int grp  = lane >> 4;
    const int l16  = lane & 15;
    const int nbase = wave * 4 + grp;

    const f32x4* p = (const f32x4*)(kv + (size_t)m * NN * DD) + (size_t)nbase * 64 + l16;
    const int STRIDE = 16 * 64;   // 16 rows per iteration, in float4 units

    // prefetch tile 0 BEFORE the qt row load
    f32x4 a0 = ld_nt(p), a1 = ld_nt(p + 16), a2 = ld_nt(p + 32), a3 = ld_nt(p + 48);

    s_qt[tid] = qt[(size_t)m * DD + tid];
    __syncthreads();

    const f32x4* qt4 = (const f32x4*)s_qt;
    const f32x4 qv0 = qt4[l16];
    const f32x4 qv1 = qt4[l16 + 16];
    const f32x4 qv2 = qt4[l16 + 32];
    const f32x4 qv3 = qt4[l16 + 48];

    f32x4 c0 = (f32x4)0.f, c1 = (f32x4)0.f, c2 = (f32x4)0.f, c3 = (f32x4)0.f;
    float lw = 0.f;

#pragma unroll 2
    for (int it = 0; it < NN / 16; ++it) {
        f32x4 b0, b1, b2, b3;
        if (it + 1 < NN / 16) {
            const f32x4* np = p + (size_t)(it + 1) * STRIDE;
            b0 = ld_nt(np); b1 = ld_nt(np + 16); b2 = ld_nt(np + 32); b3 = ld_nt(np + 48);
        }
        f32x4 t = a0 * qv0 + a1 * qv1 + a2 * qv2 + a3 * qv3;
        float pd = (t[0] + t[1]) + (t[2] + t[3]);
        pd += __shfl_xor(pd, 1);
        pd += __shfl_xor(pd, 2);
        pd += __shfl_xor(pd, 4);
        pd += __shfl_xor(pd, 8);

        const float pe = __expf(pd);
        if (l16 == 0) s_pe[it * 16 + nbase] = pe;
        lw += pe;

        c0 += pe * a0;
        c1 += pe * a1;
        c2 += pe * a2;
        c3 += pe * a3;

        a0 = b0; a1 = b1; a2 = b2; a3 = b3;
    }

    // cross-group reduce within the wave (lanes ^16, ^32)
#pragma unroll
    for (int i = 0; i < 4; ++i) {
        c0[i] += __shfl_xor(c0[i], 16); c1[i] += __shfl_xor(c1[i], 16);
        c2[i] += __shfl_xor(c2[i], 16); c3[i] += __shfl_xor(c3[i], 16);
        c0[i] += __shfl_xor(c0[i], 32); c1[i] += __shfl_xor(c1[i], 32);
        c2[i] += __shfl_xor(c2[i], 32); c3[i] += __shfl_xor(c3[i], 32);
    }
    lw += __shfl_xor(lw, 16);
    lw += __shfl_xor(lw, 32);

    {
        f32x4* wc4 = (f32x4*)(&s_wc[wave][0]);
        const f32x4 cg = (grp == 0) ? c0 : (grp == 1) ? c1 : (grp == 2) ? c2 : c3;
        wc4[grp * 16 + l16] = cg;
        if (lane == 0) s_lw[wave] = lw;
    }
    __syncthreads();

    const float L = (s_lw[0] + s_lw[1]) + (s_lw[2] + s_lw[3]);
    const float invL = 1.f / L;

    const float cd = ((s_wc[0][tid] + s_wc[1][tid]) + (s_wc[2][tid] + s_wc[3][tid])) * invL;
    c_out[(size_t)m * DD + tid] = cd;

    attn_out[(size_t)m * NN + tid]       = s_pe[tid] * invL;
    attn_out[(size_t)m * NN + tid + 256] = s_pe[tid + 256] * invL;
}

extern "C" void kernel_launch(void* const* d_in, const int* in_sizes, int n_in,
                              void* d_out, int out_size, void* d_ws, size_t ws_size,
                              hipStream_t stream) {
    const float* q_vec = (const float*)d_in[0];
    const float* kv    = (const float*)d_in[1];
    const float* wq    = (const float*)d_in[2];
    const float* wk    = (const float*)d_in[3];
    const float* wv    = (const float*)d_in[4];
    const float* wo    = (const float*)d_in[5];

    float* out  = (float*)d_out;                     // [M, D]
    float* attn = (float*)d_out + (size_t)MM * DD;   // [M, N]

    float* W1  = (float*)d_ws;                       // [D, D] (1/16 folded)
    float* W2T = W1 + DD * DD;                       // [D, D] = (wo@wv).T
    float* qt  = W2T + DD * DD;                      // [M, D]
    float* cws = qt + (size_t)MM * DD;               // [M, D]

    prep_weights<<<2 * DD, DD, 0, stream>>>(wq, wk, wv, wo, W1, W2T);
    rowgemm<16><<<MM / 16, DD, 0, stream>>>(q_vec, W1, qt);   // qt = q_vec @ W1
    attn_stream<<<MM, DD, 0, stream>>>(kv, qt, cws, attn);
    rowgemm<16><<<MM / 16, DD, 0, stream>>>(cws, W2T, out);   // out = c @ W2T
}

// Round 6
// 216.029 us; speedup vs baseline: 2.1657x; 1.0603x over previous
//
#include <hip/hip_runtime.h>
#include <math.h>

#define DD 256
#define MM 2048
#define NN 512

typedef float f32x4 __attribute__((ext_vector_type(4)));
typedef float f32x2 __attribute__((ext_vector_type(2)));

__device__ inline f32x4 ld_nt(const f32x4* p) { return __builtin_nontemporal_load(p); }

// packed fp32: d = a*b + d  (2 floats/lane per instruction)
__device__ inline void pk_fma(f32x2& d, f32x2 a, f32x2 b) {
    asm("v_pk_fma_f32 %0, %1, %2, %0" : "+v"(d) : "v"(a), "v"(b));
}
__device__ inline f32x2 pk_mul(f32x2 a, f32x2 b) {
    f32x2 d;
    asm("v_pk_mul_f32 %0, %1, %2" : "=v"(d) : "v"(a), "v"(b));
    return d;
}
__device__ inline f32x2 lo2(f32x4 v) { return __builtin_shufflevector(v, v, 0, 1); }
__device__ inline f32x2 hi2(f32x4 v) { return __builtin_shufflevector(v, v, 2, 3); }

// blocks 0..255:   W1[d][j]  = (1/16) * sum_a wq[a][d]*wk[a][j]   (qt = q_vec @ W1)
// blocks 256..511: W2T[d][j] = sum_e wo[j][e]*wv[e][d]            (out = c @ W2T)
__global__ void prep_weights(const float* __restrict__ wq, const float* __restrict__ wk,
                             const float* __restrict__ wv, const float* __restrict__ wo,
                             float* __restrict__ W1, float* __restrict__ W2T) {
    __shared__ float sA[DD];
    const int j = threadIdx.x;
    const int b = blockIdx.x;
    if (b < DD) {
        const int d = b;
        sA[j] = wq[j * DD + d];
        __syncthreads();
        float acc = 0.f;
        for (int a = 0; a < DD; ++a) acc = fmaf(sA[a], wk[a * DD + j], acc);
        W1[d * DD + j] = acc * 0.0625f;
    } else {
        const int d = b - DD;
        sA[j] = wv[j * DD + d];
        __syncthreads();
        float acc = 0.f;
        for (int e = 0; e < DD; ++e) acc = fmaf(wo[j * DD + e], sA[e], acc);
        W2T[d * DD + j] = acc;
    }
}

// R3 (208.8us) structure exactly; ONLY change: dot + accumulate use
// v_pk_fma_f32 / v_pk_mul_f32 (VOP3P packed fp32) -> ~40 VALU/iter -> ~22.
__global__ __launch_bounds__(256, 4)
void attn_fused(const float* __restrict__ q_vec, const float* __restrict__ kv,
                const float* __restrict__ W1, const float* __restrict__ W2T,
                float* __restrict__ out, float* __restrict__ attn_out) {
    __shared__ float s_pe[NN];
    __shared__ float s_lw[4];
    __shared__ float s_wc[4][DD];
    __shared__ float s_q[DD];
    __shared__ float s_qt[DD];

    const int m    = blockIdx.x;
    const int tid  = threadIdx.x;
    const int wave = tid >> 6;
    const int lane = tid & 63;
    const int grp  = lane >> 4;
    const int l16  = lane & 15;
    const int nbase = wave * 4 + grp;

    // ---- prologue: qt[m] = q_vec[m] @ W1 ----
    s_q[tid] = q_vec[(size_t)m * DD + tid];
    __syncthreads();
    {
        float a = 0.f;
#pragma unroll 8
        for (int d = 0; d < DD; ++d) a = fmaf(s_q[d], W1[d * DD + tid], a);
        s_qt[tid] = a;
    }
    __syncthreads();

    const f32x4* qt4 = (const f32x4*)s_qt;
    f32x2 qp[8];
    {
        const f32x4 q0 = qt4[l16], q1 = qt4[l16 + 16], q2 = qt4[l16 + 32], q3 = qt4[l16 + 48];
        qp[0] = lo2(q0); qp[1] = hi2(q0);
        qp[2] = lo2(q1); qp[3] = hi2(q1);
        qp[4] = lo2(q2); qp[5] = hi2(q2);
        qp[6] = lo2(q3); qp[7] = hi2(q3);
    }

    const f32x4* p = (const f32x4*)(kv + (size_t)m * NN * DD) + (size_t)nbase * 64 + l16;
    const int STRIDE = 16 * 64;   // 16 rows per iteration, f32x4 units

    f32x2 cp[8];
#pragma unroll
    for (int i = 0; i < 8; ++i) cp[i] = (f32x2)0.f;
    float lw = 0.f;

    f32x4 a0 = ld_nt(p), a1 = ld_nt(p + 16), a2 = ld_nt(p + 32), a3 = ld_nt(p + 48);

#pragma unroll 2
    for (int it = 0; it < NN / 16; ++it) {
        f32x4 b0, b1, b2, b3;
        if (it + 1 < NN / 16) {
            const f32x4* np = p + (size_t)(it + 1) * STRIDE;
            b0 = ld_nt(np); b1 = ld_nt(np + 16); b2 = ld_nt(np + 32); b3 = ld_nt(np + 48);
        }

        const f32x2 ap0 = lo2(a0), ap1 = hi2(a0), ap2 = lo2(a1), ap3 = hi2(a1);
        const f32x2 ap4 = lo2(a2), ap5 = hi2(a2), ap6 = lo2(a3), ap7 = hi2(a3);

        // dot(qt, kv_row): packed even/odd accumulation
        f32x2 t2 = pk_mul(ap0, qp[0]);
        pk_fma(t2, ap1, qp[1]);
        pk_fma(t2, ap2, qp[2]);
        pk_fma(t2, ap3, qp[3]);
        pk_fma(t2, ap4, qp[4]);
        pk_fma(t2, ap5, qp[5]);
        pk_fma(t2, ap6, qp[6]);
        pk_fma(t2, ap7, qp[7]);
        float pd = t2[0] + t2[1];
        pd += __shfl_xor(pd, 1);
        pd += __shfl_xor(pd, 2);
        pd += __shfl_xor(pd, 4);
        pd += __shfl_xor(pd, 8);

        const float pe = __expf(pd);
        if (l16 == 0) s_pe[it * 16 + nbase] = pe;
        lw += pe;

        f32x2 pe2; pe2[0] = pe; pe2[1] = pe;
        pk_fma(cp[0], pe2, ap0);
        pk_fma(cp[1], pe2, ap1);
        pk_fma(cp[2], pe2, ap2);
        pk_fma(cp[3], pe2, ap3);
        pk_fma(cp[4], pe2, ap4);
        pk_fma(cp[5], pe2, ap5);
        pk_fma(cp[6], pe2, ap6);
        pk_fma(cp[7], pe2, ap7);

        a0 = b0; a1 = b1; a2 = b2; a3 = b3;
    }

    // ---- cross-group reduce within the wave (lanes ^16, ^32) ----
#pragma unroll
    for (int i = 0; i < 8; ++i) {
#pragma unroll
        for (int j = 0; j < 2; ++j) {
            cp[i][j] += __shfl_xor(cp[i][j], 16);
            cp[i][j] += __shfl_xor(cp[i][j], 32);
        }
    }
    lw += __shfl_xor(lw, 16);
    lw += __shfl_xor(lw, 32);

    // all lanes hold the wave's full partial c; group g writes quadrant g
    {
        f32x2* wc2 = (f32x2*)(&s_wc[wave][0]);
        wc2[32 * grp + 2 * l16]     = cp[2 * grp];
        wc2[32 * grp + 2 * l16 + 1] = cp[2 * grp + 1];
        if (lane == 0) s_lw[wave] = lw;
    }
    __syncthreads();

    const float L = (s_lw[0] + s_lw[1]) + (s_lw[2] + s_lw[3]);
    const float invL = 1.f / L;

    const float cd = ((s_wc[0][tid] + s_wc[1][tid]) + (s_wc[2][tid] + s_wc[3][tid])) * invL;
    __syncthreads();
    s_q[tid] = cd;                       // reuse s_q as normalized c row
    __syncthreads();

    attn_out[(size_t)m * NN + tid]       = s_pe[tid] * invL;
    attn_out[(size_t)m * NN + tid + 256] = s_pe[tid + 256] * invL;

    // ---- epilogue: out[m] = c @ W2T ----
    float o = 0.f;
#pragma unroll 8
    for (int d = 0; d < DD; ++d) o = fmaf(s_q[d], W2T[d * DD + tid], o);
    out[(size_t)m * DD + tid] = o;
}

extern "C" void kernel_launch(void* const* d_in, const int* in_sizes, int n_in,
                              void* d_out, int out_size, void* d_ws, size_t ws_size,
                              hipStream_t stream) {
    const float* q_vec = (const float*)d_in[0];
    const float* kv    = (const float*)d_in[1];
    const float* wq    = (const float*)d_in[2];
    const float* wk    = (const float*)d_in[3];
    const float* wv    = (const float*)d_in[4];
    const float* wo    = (const float*)d_in[5];

    float* out  = (float*)d_out;                     // [M, D]
    float* attn = (float*)d_out + (size_t)MM * DD;   // [M, N]

    float* W1  = (float*)d_ws;                       // [D, D] (1/16 folded)
    float* W2T = W1 + DD * DD;                       // [D, D] = (wo@wv).T

    prep_weights<<<2 * DD, DD, 0, stream>>>(wq, wk, wv, wo, W1, W2T);
    attn_fused<<<MM, DD, 0, stream>>>(q_vec, kv, W1, W2T, out, attn);
}